// Round 7
// baseline (392.250 us; speedup 1.0000x reference)
//
#include <hip/hip_runtime.h>
#include <hip/hip_bf16.h>
#include <math.h>

typedef short short8 __attribute__((ext_vector_type(8)));
typedef float f32x4 __attribute__((ext_vector_type(4)));
typedef _Float16 f16x8 __attribute__((ext_vector_type(8)));

#define CC 768
#define NN 1024
#define RR 32768
#define MM 512
#define ZSTRIDE 786432      // C*H*W
#define OUT_ATTN_OFF 25165824
#define SPLIT_SC 2048.0f
#define INV_SC   (1.0f / 2048.0f)

static __device__ __forceinline__ short f2bf(float f) {
    __hip_bfloat16 h = __float2bfloat16(f);
    return *reinterpret_cast<short*>(&h);
}

// fast exp for x in [-2.5, +1e-6], f64 accuracy ~1e-14 rel, branch-free
static __device__ __forceinline__ double fast_exp_neg(double x) {
    const double LOG2E = 1.4426950408889634074;
    const double LN2   = 0.6931471805599453094;
    const double MAGIC = 6755399441055744.0;     // 1.5 * 2^52
    double t = x * LOG2E;
    double c = t + MAGIC;
    double n = c - MAGIC;                         // rint(t)
    int ni = (int)__double2loint(c);
    double g = (t - n) * LN2;
    double r = 2.505210838544172e-08;
    r = fma(r, g, 2.755731922398589e-07);
    r = fma(r, g, 2.7557319223985893e-06);
    r = fma(r, g, 2.48015873015873e-05);
    r = fma(r, g, 1.984126984126984e-04);
    r = fma(r, g, 1.388888888888889e-03);
    r = fma(r, g, 8.333333333333333e-03);
    r = fma(r, g, 4.1666666666666664e-02);
    r = fma(r, g, 1.6666666666666666e-01);
    r = fma(r, g, 0.5);
    r = fma(r, g, 1.0);
    r = fma(r, g, 1.0);
    double sc = __hiloint2double((1023 + ni) << 20, 0);   // 2^n
    return r * sc;
}

static __device__ __forceinline__ double fast_rcp(double x) {
    double r = (double)(1.0f / (float)x);
    r = r * (2.0 - x * r);
    r = r * (2.0 - x * r);
    return r;
}

// ---------------- Kernel Z1: transpose z -> k-contiguous f16 hi/lo + norm partials -------
// Block: 64 c x 64 n tile of one batch. grid (12, 16, 32).
__global__ __launch_bounds__(256) void zprep_kernel(const float* __restrict__ z,
                                                    _Float16* __restrict__ zhT,
                                                    _Float16* __restrict__ zLT,
                                                    double* __restrict__ zss) {
    __shared__ float tile[64][65];
    __shared__ double ssl[16][64];
    const int t = threadIdx.x;
    const int ctile = blockIdx.x, ntile = blockIdx.y, b = blockIdx.z;
    const int cq = t >> 4, nq = t & 15;
    const float* src = z + (size_t)(b * CC + ctile * 64) * NN + ntile * 64;

    double sacc[4] = {0.0, 0.0, 0.0, 0.0};
    #pragma unroll
    for (int q = 0; q < 4; ++q) {
        int cl = q * 16 + cq;
        f32x4 v = *reinterpret_cast<const f32x4*>(src + (size_t)cl * NN + nq * 4);
        #pragma unroll
        for (int j = 0; j < 4; ++j) {
            tile[cl][nq * 4 + j] = v[j];
            sacc[j] = fma((double)v[j], (double)v[j], sacc[j]);
        }
    }
    #pragma unroll
    for (int j = 0; j < 4; ++j) ssl[cq][nq * 4 + j] = sacc[j];
    __syncthreads();
    if (t < 64) {
        double s = 0.0;
        #pragma unroll
        for (int g = 0; g < 16; ++g) s += ssl[g][t];
        zss[(size_t)ctile * RR + b * NN + ntile * 64 + t] = s;
    }
    // transposed split write: 2 cells/thread, each = 8 consecutive c for one n
    #pragma unroll
    for (int e = 0; e < 2; ++e) {
        int cell = t * 2 + e;
        int nl = cell >> 3, ck = (cell & 7) * 8;
        f16x8 h8, l8;
        #pragma unroll
        for (int i = 0; i < 8; ++i) {
            float f = tile[ck + i][nl];
            _Float16 h = (_Float16)f;
            h8[i] = h;
            l8[i] = (_Float16)((f - (float)h) * SPLIT_SC);
        }
        size_t o = (size_t)(b * NN + ntile * 64 + nl) * CC + ctile * 64 + ck;
        *reinterpret_cast<f16x8*>(zhT + o) = h8;
        *reinterpret_cast<f16x8*>(zLT + o) = l8;
    }
}

// ---------------- Kernel Z2: reduce norm partials -> f64 inverse norms ----------------
__global__ __launch_bounds__(256) void znred_kernel(const double* __restrict__ zss,
                                                    double* __restrict__ zinv) {
    int r = blockIdx.x * 256 + threadIdx.x;
    double s = 0.0;
    #pragma unroll
    for (int i = 0; i < 12; ++i) s += zss[(size_t)i * RR + r];
    zinv[r] = 1.0 / fmax(sqrt(s), 1e-12);
}

// ---------------- Kernel A: memory norms + f16 hi/lo split + raw bf16 transpose ----------
__global__ __launch_bounds__(256) void prep_mem_kernel(const float* __restrict__ memory,
                                                       _Float16* __restrict__ mem_h,
                                                       _Float16* __restrict__ mem_L,
                                                       short* __restrict__ memT_bf) {
    int m = blockIdx.x;      // 0..511
    int t = threadIdx.x;
    double ss = 0.0;
    for (int c = t; c < CC; c += 256) {
        float v = memory[m * CC + c];
        ss += (double)v * (double)v;
    }
    #pragma unroll
    for (int off = 32; off > 0; off >>= 1) ss += __shfl_xor(ss, off);
    __shared__ double red[4];
    __shared__ double invs;
    if ((t & 63) == 0) red[t >> 6] = ss;
    __syncthreads();
    if (t == 0) {
        double tot = red[0] + red[1] + red[2] + red[3];
        invs = 1.0 / fmax(sqrt(tot), 1e-12);
    }
    __syncthreads();
    float inv = (float)invs;
    for (int c = t; c < CC; c += 256) {
        float v  = memory[m * CC + c];
        float nv = v * inv;
        _Float16 h = (_Float16)nv;
        float r1 = nv - (float)h;
        mem_h[m * CC + c] = h;
        mem_L[m * CC + c] = (_Float16)(r1 * SPLIT_SC);
        memT_bf[c * MM + m] = f2bf(v);
    }
}

// ---------------- Kernel B: raw scores GEMM via f16 2-split MFMA, BK=64 ----------------
// 64 rows x 128 cols per block, 256 thr = 4 waves (2 row-halves x 2 col-halves).
// Wave = 32r x 64c: fc 0..1, fn 0..3. acc[fc][fn]: row = wr*32+fc*16+(lane>>4)*4+reg,
// col = colblk*128 + wc*64 + fn*16 + (lane&15).
__global__ __launch_bounds__(256, 4) void scores_gemm_kernel(const _Float16* __restrict__ zhT,
                                                             const _Float16* __restrict__ zLT,
                                                             const _Float16* __restrict__ mem_h,
                                                             const _Float16* __restrict__ mem_L,
                                                             float* __restrict__ out_scores) {
    __shared__ _Float16 AT[2][2][64][72];   // 36 KB, pad-72 -> 2-way-free frag reads
    const int t    = threadIdx.x;
    const int lane = t & 63;
    const int wv   = t >> 6;
    const int lrow = lane & 15;
    const int gk   = lane >> 4;
    const int wr   = wv >> 1, wc = wv & 1;
    // XCD-bijective decode: 4 col-siblings of a rowblock share dispatch slot mod 8
    const int d = blockIdx.x;
    const int colblk = (d >> 3) & 3;
    const int rowblk = (d & 7) | ((d >> 5) << 3);
    const int row0 = rowblk * 64;
    const int b    = row0 >> 10;
    const int n0   = row0 & 1023;
    const int c0   = colblk * 128 + wc * 64;

    const _Float16* zsp[2] = {zhT, zLT};

    f32x4 am[2][4], ax[2][4];
    #pragma unroll
    for (int fc = 0; fc < 2; ++fc)
        #pragma unroll
        for (int fn = 0; fn < 4; ++fn) {
            am[fc][fn] = (f32x4){0.f, 0.f, 0.f, 0.f};
            ax[fc][fn] = (f32x4){0.f, 0.f, 0.f, 0.f};
        }

    // staging: 4 cells/thread: cell = t + 256e -> sp=cell>>9, cc=cell&511, sn=cc>>3, kc=(cc&7)*8
    // prologue: stage kt=0
    #pragma unroll
    for (int e = 0; e < 4; ++e) {
        int sp = e >> 1;
        int cc = t + 256 * (e & 1);
        int sn = cc >> 3, kc = (cc & 7) * 8;
        f16x8 v = *reinterpret_cast<const f16x8*>(
            zsp[sp] + (size_t)(b * NN + n0 + sn) * CC + kc);
        *reinterpret_cast<f16x8*>(&AT[0][sp][sn][kc]) = v;
    }
    __syncthreads();

    #pragma unroll 1
    for (int kt = 0; kt < 12; ++kt) {
        const int cur = kt & 1;
        const bool dostage = (kt < 11);
        f16x8 nx[4];
        if (dostage) {
            #pragma unroll
            for (int e = 0; e < 4; ++e) {
                int sp = e >> 1;
                int cc = t + 256 * (e & 1);
                int sn = cc >> 3, kc = (cc & 7) * 8;
                nx[e] = *reinterpret_cast<const f16x8*>(
                    zsp[sp] + (size_t)(b * NN + n0 + sn) * CC + (kt + 1) * 64 + kc);
            }
        }
        #pragma unroll
        for (int ks = 0; ks < 2; ++ks) {
            f16x8 ah[2], aL[2];
            #pragma unroll
            for (int fc = 0; fc < 2; ++fc) {
                ah[fc] = *reinterpret_cast<const f16x8*>(
                    &AT[cur][0][wr * 32 + fc * 16 + lrow][ks * 32 + gk * 8]);
                aL[fc] = *reinterpret_cast<const f16x8*>(
                    &AT[cur][1][wr * 32 + fc * 16 + lrow][ks * 32 + gk * 8]);
            }
            f16x8 bh[4], bL[4];
            #pragma unroll
            for (int fn = 0; fn < 4; ++fn) {
                const size_t moff = (size_t)(c0 + fn * 16 + lrow) * CC
                                    + kt * 64 + ks * 32 + gk * 8;
                bh[fn] = *reinterpret_cast<const f16x8*>(mem_h + moff);
                bL[fn] = *reinterpret_cast<const f16x8*>(mem_L + moff);
            }
            #pragma unroll
            for (int fn = 0; fn < 4; ++fn)
                #pragma unroll
                for (int fc = 0; fc < 2; ++fc) {
                    am[fc][fn] = __builtin_amdgcn_mfma_f32_16x16x32_f16(ah[fc], bh[fn], am[fc][fn], 0, 0, 0);
                    ax[fc][fn] = __builtin_amdgcn_mfma_f32_16x16x32_f16(aL[fc], bh[fn], ax[fc][fn], 0, 0, 0);
                    ax[fc][fn] = __builtin_amdgcn_mfma_f32_16x16x32_f16(ah[fc], bL[fn], ax[fc][fn], 0, 0, 0);
                }
        }
        if (dostage) {
            #pragma unroll
            for (int e = 0; e < 4; ++e) {
                int sp = e >> 1;
                int cc = t + 256 * (e & 1);
                int sn = cc >> 3, kc = (cc & 7) * 8;
                *reinterpret_cast<f16x8*>(&AT[cur ^ 1][sp][sn][kc]) = nx[e];
            }
        }
        __syncthreads();
    }

    #pragma unroll
    for (int fc = 0; fc < 2; ++fc)
        #pragma unroll
        for (int fn = 0; fn < 4; ++fn)
            #pragma unroll
            for (int rg = 0; rg < 4; ++rg) {
                int row = row0 + wr * 32 + fc * 16 + gk * 4 + rg;
                int col = c0 + fn * 16 + lrow;
                out_scores[(size_t)row * MM + col] = am[fc][fn][rg] + ax[fc][fn][rg] * INV_SC;
            }
}

// ---------------- Kernel C: in-place softmax + hardshrink + renorm (f64) -------
__global__ __launch_bounds__(256) void epilogue_kernel(float* __restrict__ attn,
                                                       const double* __restrict__ zinv_ws) {
    const int t    = threadIdx.x;
    const int lane = t & 63;
    const int wv   = t >> 6;
    const int row0 = blockIdx.x * 64;

    #pragma unroll 1
    for (int i = 0; i < 16; ++i) {
        int row = row0 + wv * 16 + i;
        double zi = zinv_ws[row];
        float* rp = attn + (size_t)row * MM;
        f32x4 x0 = *reinterpret_cast<const f32x4*>(&rp[lane * 4]);
        f32x4 x1 = *reinterpret_cast<const f32x4*>(&rp[256 + lane * 4]);
        double s0 = (double)x0[0] * zi, s1 = (double)x0[1] * zi;
        double s2 = (double)x0[2] * zi, s3 = (double)x0[3] * zi;
        double s4 = (double)x1[0] * zi, s5 = (double)x1[1] * zi;
        double s6 = (double)x1[2] * zi, s7 = (double)x1[3] * zi;
        double mx = fmax(fmax(fmax(s0, s1), fmax(s2, s3)),
                         fmax(fmax(s4, s5), fmax(s6, s7)));
        #pragma unroll
        for (int off = 32; off > 0; off >>= 1) mx = fmax(mx, __shfl_xor(mx, off));
        double p0 = fast_exp_neg(s0 - mx), p1 = fast_exp_neg(s1 - mx);
        double p2 = fast_exp_neg(s2 - mx), p3 = fast_exp_neg(s3 - mx);
        double p4 = fast_exp_neg(s4 - mx), p5 = fast_exp_neg(s5 - mx);
        double p6 = fast_exp_neg(s6 - mx), p7 = fast_exp_neg(s7 - mx);
        double Z = ((p0 + p1) + (p2 + p3)) + ((p4 + p5) + (p6 + p7));
        #pragma unroll
        for (int off = 32; off > 0; off >>= 1) Z += __shfl_xor(Z, off);
        double iZ = fast_rcp(Z);
        const double LAM = 1.0 / 512.0;
        double w0 = p0 * iZ, w1 = p1 * iZ, w2 = p2 * iZ, w3 = p3 * iZ;
        double w4 = p4 * iZ, w5 = p5 * iZ, w6 = p6 * iZ, w7 = p7 * iZ;
        double d0 = w0 - LAM, d1 = w1 - LAM, d2 = w2 - LAM, d3 = w3 - LAM;
        double d4 = w4 - LAM, d5 = w5 - LAM, d6 = w6 - LAM, d7 = w7 - LAM;
        double e0 = (d0 > 0.0 ? d0 : 0.0) * w0 * fast_rcp(fabs(d0) + 1e-8);
        double e1 = (d1 > 0.0 ? d1 : 0.0) * w1 * fast_rcp(fabs(d1) + 1e-8);
        double e2 = (d2 > 0.0 ? d2 : 0.0) * w2 * fast_rcp(fabs(d2) + 1e-8);
        double e3 = (d3 > 0.0 ? d3 : 0.0) * w3 * fast_rcp(fabs(d3) + 1e-8);
        double e4 = (d4 > 0.0 ? d4 : 0.0) * w4 * fast_rcp(fabs(d4) + 1e-8);
        double e5 = (d5 > 0.0 ? d5 : 0.0) * w5 * fast_rcp(fabs(d5) + 1e-8);
        double e6 = (d6 > 0.0 ? d6 : 0.0) * w6 * fast_rcp(fabs(d6) + 1e-8);
        double e7 = (d7 > 0.0 ? d7 : 0.0) * w7 * fast_rcp(fabs(d7) + 1e-8);
        double S = ((e0 + e1) + (e2 + e3)) + ((e4 + e5) + (e6 + e7));
        #pragma unroll
        for (int off = 32; off > 0; off >>= 1) S += __shfl_xor(S, off);
        double rinv = fast_rcp(S + 1e-8);
        f32x4 o0 = { (float)(e0 * rinv), (float)(e1 * rinv),
                     (float)(e2 * rinv), (float)(e3 * rinv) };
        f32x4 o1 = { (float)(e4 * rinv), (float)(e5 * rinv),
                     (float)(e6 * rinv), (float)(e7 * rinv) };
        *reinterpret_cast<f32x4*>(&rp[lane * 4])       = o0;
        *reinterpret_cast<f32x4*>(&rp[256 + lane * 4]) = o1;
    }
}

// ---------------- Kernel D: z_hat = attn @ memory via bf16 MFMA ----------------
__global__ __launch_bounds__(256) void readout_kernel(const short* __restrict__ memT_bf,
                                                      const float* __restrict__ attn,
                                                      float* __restrict__ out) {
    __shared__ short At[64][40];    // 64 c-rows x 32 k, padded
    __shared__ short Bt[128][40];   // 128 n-rows x 32 k
    int t = threadIdx.x;
    int c0     = blockIdx.x * 64;
    int rowblk = blockIdx.y * 128;
    int b  = rowblk >> 10;
    int nb = rowblk & 1023;
    int lane = t & 63, wv = t >> 6;

    f32x4 acc[4][2];
    #pragma unroll
    for (int fc = 0; fc < 4; ++fc)
        #pragma unroll
        for (int fn = 0; fn < 2; ++fn) acc[fc][fn] = (f32x4){0.f, 0.f, 0.f, 0.f};

    for (int m0 = 0; m0 < MM; m0 += 32) {
        __syncthreads();
        {   // stage A: 64 x 32 bf16
            int r = t >> 2, ko = (t & 3) * 8;
            short8 v = *reinterpret_cast<const short8*>(&memT_bf[(c0 + r) * MM + m0 + ko]);
            *reinterpret_cast<short8*>(&At[r][ko]) = v;
        }
        {   // stage B: 128 x 32, attn f32 -> bf16, vectorized
            int r = t >> 1, ko = (t & 1) * 16;
            const f32x4* src = reinterpret_cast<const f32x4*>(
                &attn[(size_t)(rowblk + r) * MM + m0 + ko]);
            f32x4 v0 = src[0], v1 = src[1], v2 = src[2], v3 = src[3];
            short8 s0 = { f2bf(v0[0]), f2bf(v0[1]), f2bf(v0[2]), f2bf(v0[3]),
                          f2bf(v1[0]), f2bf(v1[1]), f2bf(v1[2]), f2bf(v1[3]) };
            short8 s1 = { f2bf(v2[0]), f2bf(v2[1]), f2bf(v2[2]), f2bf(v2[3]),
                          f2bf(v3[0]), f2bf(v3[1]), f2bf(v3[2]), f2bf(v3[3]) };
            *reinterpret_cast<short8*>(&Bt[r][ko])     = s0;
            *reinterpret_cast<short8*>(&Bt[r][ko + 8]) = s1;
        }
        __syncthreads();
        short8 af[4], bfr[2];
        #pragma unroll
        for (int fc = 0; fc < 4; ++fc)
            af[fc] = *reinterpret_cast<const short8*>(&At[fc * 16 + (lane & 15)][(lane >> 4) * 8]);
        #pragma unroll
        for (int fn = 0; fn < 2; ++fn)
            bfr[fn] = *reinterpret_cast<const short8*>(&Bt[wv * 32 + fn * 16 + (lane & 15)][(lane >> 4) * 8]);
        #pragma unroll
        for (int fc = 0; fc < 4; ++fc)
            #pragma unroll
            for (int fn = 0; fn < 2; ++fn)
                acc[fc][fn] = __builtin_amdgcn_mfma_f32_16x16x32_bf16(af[fc], bfr[fn], acc[fc][fn], 0, 0, 0);
    }

    int cg = lane >> 4, cl = lane & 15;
    #pragma unroll
    for (int fc = 0; fc < 4; ++fc)
        #pragma unroll
        for (int fn = 0; fn < 2; ++fn)
            #pragma unroll
            for (int reg = 0; reg < 4; ++reg) {
                int c = c0 + fc * 16 + cg * 4 + reg;
                int n = nb + wv * 32 + fn * 16 + cl;
                out[(size_t)b * ZSTRIDE + (size_t)c * NN + n] = acc[fc][fn][reg];
            }
}

extern "C" void kernel_launch(void* const* d_in, const int* in_sizes, int n_in,
                              void* d_out, int out_size, void* d_ws, size_t ws_size,
                              hipStream_t stream) {
    const float* z      = (const float*)d_in[0];
    const float* memory = (const float*)d_in[1];
    float* out      = (float*)d_out;
    float* out_attn = out + OUT_ATTN_OFF;

    // z-split scratch lives in the (not-yet-written) z_hat region of d_out:
    // zhT 48MB + zLT 48MB <= 96MB < z_hat's 100.66MB. readout overwrites it last.
    _Float16* zhT = (_Float16*)d_out;
    _Float16* zLT = (_Float16*)((char*)d_out + 50331648);

    char* wsb = (char*)d_ws;
    _Float16* mem_h   = (_Float16*)wsb;               // 786432 B
    _Float16* mem_L   = (_Float16*)(wsb + 786432);    // 786432 B
    short*    memT_bf = (short*)(wsb + 1572864);      // 786432 B
    double*   zinv_ws = (double*)(wsb + 2359296);     // 262144 B
    double*   zss     = (double*)(wsb + 2621440);     // 12*32768*8 = 3145728 B

    zprep_kernel<<<dim3(12, 16, 32), 256, 0, stream>>>(z, zhT, zLT, zss);
    znred_kernel<<<RR / 256, 256, 0, stream>>>(zss, zinv_ws);
    prep_mem_kernel<<<512, 256, 0, stream>>>(memory, mem_h, mem_L, memT_bf);
    scores_gemm_kernel<<<2048, 256, 0, stream>>>(zhT, zLT, mem_h, mem_L, out_attn);
    epilogue_kernel<<<RR / 64, 256, 0, stream>>>(out_attn, zinv_ws);
    readout_kernel<<<dim3(CC / 64, RR / 128), 256, 0, stream>>>(memT_bf, out_attn, out);
}

// Round 8
// 256.069 us; speedup vs baseline: 1.5318x; 1.5318x over previous
//
#include <hip/hip_runtime.h>
#include <hip/hip_bf16.h>
#include <math.h>

typedef short short8 __attribute__((ext_vector_type(8)));
typedef float f32x4 __attribute__((ext_vector_type(4)));
typedef _Float16 f16x8 __attribute__((ext_vector_type(8)));

#define CC 768
#define NN 1024
#define RR 32768
#define MM 512
#define ZSTRIDE 786432      // C*H*W
#define OUT_ATTN_OFF 25165824
#define SPLIT_SC 2048.0f
#define INV_SC   (1.0f / 2048.0f)

static __device__ __forceinline__ short f2bf(float f) {
    __hip_bfloat16 h = __float2bfloat16(f);
    return *reinterpret_cast<short*>(&h);
}

// fast exp for x in [-2.5, +1e-6], f64 accuracy ~1e-14 rel, branch-free
static __device__ __forceinline__ double fast_exp_neg(double x) {
    const double LOG2E = 1.4426950408889634074;
    const double LN2   = 0.6931471805599453094;
    const double MAGIC = 6755399441055744.0;     // 1.5 * 2^52
    double t = x * LOG2E;
    double c = t + MAGIC;
    double n = c - MAGIC;                         // rint(t)
    int ni = (int)__double2loint(c);
    double g = (t - n) * LN2;
    double r = 2.505210838544172e-08;
    r = fma(r, g, 2.755731922398589e-07);
    r = fma(r, g, 2.7557319223985893e-06);
    r = fma(r, g, 2.48015873015873e-05);
    r = fma(r, g, 1.984126984126984e-04);
    r = fma(r, g, 1.388888888888889e-03);
    r = fma(r, g, 8.333333333333333e-03);
    r = fma(r, g, 4.1666666666666664e-02);
    r = fma(r, g, 1.6666666666666666e-01);
    r = fma(r, g, 0.5);
    r = fma(r, g, 1.0);
    r = fma(r, g, 1.0);
    double sc = __hiloint2double((1023 + ni) << 20, 0);   // 2^n
    return r * sc;
}

static __device__ __forceinline__ double fast_rcp(double x) {
    double r = (double)(1.0f / (float)x);
    r = r * (2.0 - x * r);
    r = r * (2.0 - x * r);
    return r;
}

// ---------------- Kernel A: memory norms + f16 hi/lo split + raw bf16 transpose ----------
__global__ __launch_bounds__(256) void prep_mem_kernel(const float* __restrict__ memory,
                                                       _Float16* __restrict__ mem_h,
                                                       _Float16* __restrict__ mem_L,
                                                       short* __restrict__ memT_bf) {
    int m = blockIdx.x;      // 0..511
    int t = threadIdx.x;
    double ss = 0.0;
    for (int c = t; c < CC; c += 256) {
        float v = memory[m * CC + c];
        ss += (double)v * (double)v;
    }
    #pragma unroll
    for (int off = 32; off > 0; off >>= 1) ss += __shfl_xor(ss, off);
    __shared__ double red[4];
    __shared__ double invs;
    if ((t & 63) == 0) red[t >> 6] = ss;
    __syncthreads();
    if (t == 0) {
        double tot = red[0] + red[1] + red[2] + red[3];
        invs = 1.0 / fmax(sqrt(tot), 1e-12);
    }
    __syncthreads();
    float inv = (float)invs;
    for (int c = t; c < CC; c += 256) {
        float v  = memory[m * CC + c];
        float nv = v * inv;
        _Float16 h = (_Float16)nv;
        float r1 = nv - (float)h;
        mem_h[m * CC + c] = h;
        mem_L[m * CC + c] = (_Float16)(r1 * SPLIT_SC);
        memT_bf[c * MM + m] = f2bf(v);
    }
}

// ---------------- Kernel B: scores GEMM, f16 2-split, both operands LDS-staged ----------
// BM=64 x BN=128 x BK=32. 256 thr = 4 waves; wave (wr=wv>>1, wc=wv&1) = 32r x 64c.
// acc[fc][fn]: row = row0 + wr*32 + fc*16 + (lane>>4)*4 + reg,
//              col = colblk*128 + wc*64 + fn*16 + (lane&15).
__global__ __launch_bounds__(256, 2) void scores_gemm_kernel(const float* __restrict__ z,
                                                             const _Float16* __restrict__ mem_h,
                                                             const _Float16* __restrict__ mem_L,
                                                             float* __restrict__ out_scores,
                                                             double* __restrict__ zinv_ws) {
    __shared__ _Float16 AT[2][2][64][36];    // [buf][h/L][row][k+pad]  18 KB
    __shared__ _Float16 BT[2][2][128][36];   // [buf][h/L][col][k+pad]  36.9 KB
    __shared__ double ssred[256];

    const int t    = threadIdx.x;
    const int lane = t & 63;
    const int wv   = t >> 6;
    const int lrow = lane & 15;
    const int gk   = lane >> 4;
    const int wr   = wv >> 1, wc = wv & 1;
    // XCD-bijective decode (col-siblings of a rowblock share dispatch slot mod 8)
    const int d = blockIdx.x;
    const int colblk = (d >> 3) & 3;
    const int rowblk = (d & 7) | ((d >> 5) << 3);
    const int row0 = rowblk * 64;
    const int b    = row0 >> 10;
    const int n0   = row0 & 1023;
    const int cB0  = colblk * 128;

    // A staging coords: thread feeds row an, k-chunk ak8 (8 k's)
    const int an  = t & 63;
    const int ak8 = (t >> 6) * 8;
    const float* zA = z + (size_t)b * ZSTRIDE + n0 + an;
    // B staging coords: thread feeds col bc, 16 k's at bk16
    const int bc   = t >> 1;
    const int bk16 = (t & 1) * 16;
    const _Float16* mhB = mem_h + (size_t)(cB0 + bc) * CC + bk16;
    const _Float16* mLB = mem_L + (size_t)(cB0 + bc) * CC + bk16;

    double ss = 0.0;
    f32x4 am[2][4], ax[2][4];
    #pragma unroll
    for (int fc = 0; fc < 2; ++fc)
        #pragma unroll
        for (int fn = 0; fn < 4; ++fn) {
            am[fc][fn] = (f32x4){0.f, 0.f, 0.f, 0.f};
            ax[fc][fn] = (f32x4){0.f, 0.f, 0.f, 0.f};
        }

    #define LOADS(kt_, av_, bvh_, bvL_)                                        \
        do {                                                                   \
            _Pragma("unroll")                                                  \
            for (int j = 0; j < 8; ++j)                                        \
                av_[j] = zA[(size_t)((kt_) * 32 + ak8 + j) * NN];              \
            bvh_[0] = *reinterpret_cast<const f16x8*>(mhB + (kt_) * 32);       \
            bvh_[1] = *reinterpret_cast<const f16x8*>(mhB + (kt_) * 32 + 8);   \
            bvL_[0] = *reinterpret_cast<const f16x8*>(mLB + (kt_) * 32);       \
            bvL_[1] = *reinterpret_cast<const f16x8*>(mLB + (kt_) * 32 + 8);   \
        } while (0)

    #define WRITES(bb_, av_, bvh_, bvL_)                                       \
        do {                                                                   \
            f16x8 h8, l8;                                                      \
            _Pragma("unroll")                                                  \
            for (int j = 0; j < 8; ++j) {                                      \
                float v = av_[j];                                              \
                ss = fma((double)v, (double)v, ss);                            \
                _Float16 h = (_Float16)v;                                      \
                h8[j] = h;                                                     \
                l8[j] = (_Float16)((v - (float)h) * SPLIT_SC);                 \
            }                                                                  \
            *reinterpret_cast<f16x8*>(&AT[bb_][0][an][ak8]) = h8;              \
            *reinterpret_cast<f16x8*>(&AT[bb_][1][an][ak8]) = l8;              \
            *reinterpret_cast<f16x8*>(&BT[bb_][0][bc][bk16])     = bvh_[0];    \
            *reinterpret_cast<f16x8*>(&BT[bb_][0][bc][bk16 + 8]) = bvh_[1];    \
            *reinterpret_cast<f16x8*>(&BT[bb_][1][bc][bk16])     = bvL_[0];    \
            *reinterpret_cast<f16x8*>(&BT[bb_][1][bc][bk16 + 8]) = bvL_[1];    \
        } while (0)

    {   // prologue: stage kt=0
        float av[8]; f16x8 bvh[2], bvL[2];
        LOADS(0, av, bvh, bvL);
        WRITES(0, av, bvh, bvL);
    }
    __syncthreads();

    #pragma unroll 1
    for (int kt = 0; kt < 24; ++kt) {
        const int cur = kt & 1;
        float av[8]; f16x8 bvh[2], bvL[2];
        if (kt < 23) LOADS(kt + 1, av, bvh, bvL);   // T14: issue early

        f16x8 ah[2], aL[2];
        #pragma unroll
        for (int fc = 0; fc < 2; ++fc) {
            ah[fc] = *reinterpret_cast<const f16x8*>(&AT[cur][0][wr * 32 + fc * 16 + lrow][gk * 8]);
            aL[fc] = *reinterpret_cast<const f16x8*>(&AT[cur][1][wr * 32 + fc * 16 + lrow][gk * 8]);
        }
        f16x8 bh[4], bL[4];
        #pragma unroll
        for (int fn = 0; fn < 4; ++fn) {
            bh[fn] = *reinterpret_cast<const f16x8*>(&BT[cur][0][wc * 64 + fn * 16 + lrow][gk * 8]);
            bL[fn] = *reinterpret_cast<const f16x8*>(&BT[cur][1][wc * 64 + fn * 16 + lrow][gk * 8]);
        }
        #pragma unroll
        for (int fn = 0; fn < 4; ++fn)
            #pragma unroll
            for (int fc = 0; fc < 2; ++fc) {
                am[fc][fn] = __builtin_amdgcn_mfma_f32_16x16x32_f16(ah[fc], bh[fn], am[fc][fn], 0, 0, 0);
                ax[fc][fn] = __builtin_amdgcn_mfma_f32_16x16x32_f16(aL[fc], bh[fn], ax[fc][fn], 0, 0, 0);
                ax[fc][fn] = __builtin_amdgcn_mfma_f32_16x16x32_f16(ah[fc], bL[fn], ax[fc][fn], 0, 0, 0);
            }

        if (kt < 23) WRITES(cur ^ 1, av, bvh, bvL);  // write-late into other buffer
        __syncthreads();
    }
    #undef LOADS
    #undef WRITES

    // ---- store raw scores ----
    #pragma unroll
    for (int fc = 0; fc < 2; ++fc)
        #pragma unroll
        for (int fn = 0; fn < 4; ++fn)
            #pragma unroll
            for (int rg = 0; rg < 4; ++rg) {
                int row = row0 + wr * 32 + fc * 16 + gk * 4 + rg;
                int col = cB0 + wc * 64 + fn * 16 + lrow;
                out_scores[(size_t)row * MM + col] = am[fc][fn][rg] + ax[fc][fn][rg] * INV_SC;
            }

    // ---- z row inverse norms (each thread covered k = {kt*32+ak8..+7}) ----
    ssred[t] = ss;
    __syncthreads();
    if (colblk == 0 && t < 64) {
        double tot = ssred[t] + ssred[t + 64] + ssred[t + 128] + ssred[t + 192];
        zinv_ws[row0 + t] = 1.0 / fmax(sqrt(tot), 1e-12);
    }
}

// ---------------- Kernel C: in-place softmax + hardshrink + renorm (f64) -------
__global__ __launch_bounds__(256) void epilogue_kernel(float* __restrict__ attn,
                                                       const double* __restrict__ zinv_ws) {
    const int t    = threadIdx.x;
    const int lane = t & 63;
    const int wv   = t >> 6;
    const int row0 = blockIdx.x * 64;

    #pragma unroll 1
    for (int i = 0; i < 16; ++i) {
        int row = row0 + wv * 16 + i;
        double zi = zinv_ws[row];
        float* rp = attn + (size_t)row * MM;
        f32x4 x0 = *reinterpret_cast<const f32x4*>(&rp[lane * 4]);
        f32x4 x1 = *reinterpret_cast<const f32x4*>(&rp[256 + lane * 4]);
        double s0 = (double)x0[0] * zi, s1 = (double)x0[1] * zi;
        double s2 = (double)x0[2] * zi, s3 = (double)x0[3] * zi;
        double s4 = (double)x1[0] * zi, s5 = (double)x1[1] * zi;
        double s6 = (double)x1[2] * zi, s7 = (double)x1[3] * zi;
        double mx = fmax(fmax(fmax(s0, s1), fmax(s2, s3)),
                         fmax(fmax(s4, s5), fmax(s6, s7)));
        #pragma unroll
        for (int off = 32; off > 0; off >>= 1) mx = fmax(mx, __shfl_xor(mx, off));
        double p0 = fast_exp_neg(s0 - mx), p1 = fast_exp_neg(s1 - mx);
        double p2 = fast_exp_neg(s2 - mx), p3 = fast_exp_neg(s3 - mx);
        double p4 = fast_exp_neg(s4 - mx), p5 = fast_exp_neg(s5 - mx);
        double p6 = fast_exp_neg(s6 - mx), p7 = fast_exp_neg(s7 - mx);
        double Z = ((p0 + p1) + (p2 + p3)) + ((p4 + p5) + (p6 + p7));
        #pragma unroll
        for (int off = 32; off > 0; off >>= 1) Z += __shfl_xor(Z, off);
        double iZ = fast_rcp(Z);
        const double LAM = 1.0 / 512.0;
        double w0 = p0 * iZ, w1 = p1 * iZ, w2 = p2 * iZ, w3 = p3 * iZ;
        double w4 = p4 * iZ, w5 = p5 * iZ, w6 = p6 * iZ, w7 = p7 * iZ;
        double d0 = w0 - LAM, d1 = w1 - LAM, d2 = w2 - LAM, d3 = w3 - LAM;
        double d4 = w4 - LAM, d5 = w5 - LAM, d6 = w6 - LAM, d7 = w7 - LAM;
        double e0 = (d0 > 0.0 ? d0 : 0.0) * w0 * fast_rcp(fabs(d0) + 1e-8);
        double e1 = (d1 > 0.0 ? d1 : 0.0) * w1 * fast_rcp(fabs(d1) + 1e-8);
        double e2 = (d2 > 0.0 ? d2 : 0.0) * w2 * fast_rcp(fabs(d2) + 1e-8);
        double e3 = (d3 > 0.0 ? d3 : 0.0) * w3 * fast_rcp(fabs(d3) + 1e-8);
        double e4 = (d4 > 0.0 ? d4 : 0.0) * w4 * fast_rcp(fabs(d4) + 1e-8);
        double e5 = (d5 > 0.0 ? d5 : 0.0) * w5 * fast_rcp(fabs(d5) + 1e-8);
        double e6 = (d6 > 0.0 ? d6 : 0.0) * w6 * fast_rcp(fabs(d6) + 1e-8);
        double e7 = (d7 > 0.0 ? d7 : 0.0) * w7 * fast_rcp(fabs(d7) + 1e-8);
        double S = ((e0 + e1) + (e2 + e3)) + ((e4 + e5) + (e6 + e7));
        #pragma unroll
        for (int off = 32; off > 0; off >>= 1) S += __shfl_xor(S, off);
        double rinv = fast_rcp(S + 1e-8);
        f32x4 o0 = { (float)(e0 * rinv), (float)(e1 * rinv),
                     (float)(e2 * rinv), (float)(e3 * rinv) };
        f32x4 o1 = { (float)(e4 * rinv), (float)(e5 * rinv),
                     (float)(e6 * rinv), (float)(e7 * rinv) };
        *reinterpret_cast<f32x4*>(&rp[lane * 4])       = o0;
        *reinterpret_cast<f32x4*>(&rp[256 + lane * 4]) = o1;
    }
}

// ---------------- Kernel D: z_hat = attn @ memory via bf16 MFMA ----------------
__global__ __launch_bounds__(256) void readout_kernel(const short* __restrict__ memT_bf,
                                                      const float* __restrict__ attn,
                                                      float* __restrict__ out) {
    __shared__ short At[64][40];    // 64 c-rows x 32 k, padded
    __shared__ short Bt[128][40];   // 128 n-rows x 32 k
    int t = threadIdx.x;
    int c0     = blockIdx.x * 64;
    int rowblk = blockIdx.y * 128;
    int b  = rowblk >> 10;
    int nb = rowblk & 1023;
    int lane = t & 63, wv = t >> 6;

    f32x4 acc[4][2];
    #pragma unroll
    for (int fc = 0; fc < 4; ++fc)
        #pragma unroll
        for (int fn = 0; fn < 2; ++fn) acc[fc][fn] = (f32x4){0.f, 0.f, 0.f, 0.f};

    for (int m0 = 0; m0 < MM; m0 += 32) {
        __syncthreads();
        {   // stage A: 64 x 32 bf16
            int r = t >> 2, ko = (t & 3) * 8;
            short8 v = *reinterpret_cast<const short8*>(&memT_bf[(c0 + r) * MM + m0 + ko]);
            *reinterpret_cast<short8*>(&At[r][ko]) = v;
        }
        {   // stage B: 128 x 32, attn f32 -> bf16, vectorized
            int r = t >> 1, ko = (t & 1) * 16;
            const f32x4* src = reinterpret_cast<const f32x4*>(
                &attn[(size_t)(rowblk + r) * MM + m0 + ko]);
            f32x4 v0 = src[0], v1 = src[1], v2 = src[2], v3 = src[3];
            short8 s0 = { f2bf(v0[0]), f2bf(v0[1]), f2bf(v0[2]), f2bf(v0[3]),
                          f2bf(v1[0]), f2bf(v1[1]), f2bf(v1[2]), f2bf(v1[3]) };
            short8 s1 = { f2bf(v2[0]), f2bf(v2[1]), f2bf(v2[2]), f2bf(v2[3]),
                          f2bf(v3[0]), f2bf(v3[1]), f2bf(v3[2]), f2bf(v3[3]) };
            *reinterpret_cast<short8*>(&Bt[r][ko])     = s0;
            *reinterpret_cast<short8*>(&Bt[r][ko + 8]) = s1;
        }
        __syncthreads();
        short8 af[4], bfr[2];
        #pragma unroll
        for (int fc = 0; fc < 4; ++fc)
            af[fc] = *reinterpret_cast<const short8*>(&At[fc * 16 + (lane & 15)][(lane >> 4) * 8]);
        #pragma unroll
        for (int fn = 0; fn < 2; ++fn)
            bfr[fn] = *reinterpret_cast<const short8*>(&Bt[wv * 32 + fn * 16 + (lane & 15)][(lane >> 4) * 8]);
        #pragma unroll
        for (int fc = 0; fc < 4; ++fc)
            #pragma unroll
            for (int fn = 0; fn < 2; ++fn)
                acc[fc][fn] = __builtin_amdgcn_mfma_f32_16x16x32_bf16(af[fc], bfr[fn], acc[fc][fn], 0, 0, 0);
    }

    int cg = lane >> 4, cl = lane & 15;
    #pragma unroll
    for (int fc = 0; fc < 4; ++fc)
        #pragma unroll
        for (int fn = 0; fn < 2; ++fn)
            #pragma unroll
            for (int reg = 0; reg < 4; ++reg) {
                int c = c0 + fc * 16 + cg * 4 + reg;
                int n = nb + wv * 32 + fn * 16 + cl;
                out[(size_t)b * ZSTRIDE + (size_t)c * NN + n] = acc[fc][fn][reg];
            }
}

extern "C" void kernel_launch(void* const* d_in, const int* in_sizes, int n_in,
                              void* d_out, int out_size, void* d_ws, size_t ws_size,
                              hipStream_t stream) {
    const float* z      = (const float*)d_in[0];
    const float* memory = (const float*)d_in[1];
    float* out      = (float*)d_out;
    float* out_attn = out + OUT_ATTN_OFF;

    char* wsb = (char*)d_ws;
    _Float16* mem_h   = (_Float16*)wsb;               // 786432 B
    _Float16* mem_L   = (_Float16*)(wsb + 786432);    // 786432 B
    short*    memT_bf = (short*)(wsb + 1572864);      // 786432 B
    double*   zinv_ws = (double*)(wsb + 2359296);     // 262144 B

    prep_mem_kernel<<<512, 256, 0, stream>>>(memory, mem_h, mem_L, memT_bf);
    scores_gemm_kernel<<<2048, 256, 0, stream>>>(z, mem_h, mem_L, out_attn, zinv_ws);
    epilogue_kernel<<<RR / 64, 256, 0, stream>>>(out_attn, zinv_ws);
    readout_kernel<<<dim3(CC / 64, RR / 128), 256, 0, stream>>>(memT_bf, out_attn, out);
}

// Round 9
// 207.677 us; speedup vs baseline: 1.8888x; 1.2330x over previous
//
#include <hip/hip_runtime.h>
#include <hip/hip_bf16.h>
#include <math.h>

typedef short short8 __attribute__((ext_vector_type(8)));
typedef float f32x4 __attribute__((ext_vector_type(4)));
typedef _Float16 f16x8 __attribute__((ext_vector_type(8)));

#define CC 768
#define NN 1024
#define RR 32768
#define MM 512
#define ZSTRIDE 786432      // C*H*W
#define OUT_ATTN_OFF 25165824
#define SPLIT_SC 2048.0f
#define INV_SC   (1.0f / 2048.0f)

static __device__ __forceinline__ short f2bf(float f) {
    __hip_bfloat16 h = __float2bfloat16(f);
    return *reinterpret_cast<short*>(&h);
}

// fast exp for x in [-2.5, +1e-6], f64 accuracy ~1e-14 rel, branch-free
static __device__ __forceinline__ double fast_exp_neg(double x) {
    const double LOG2E = 1.4426950408889634074;
    const double LN2   = 0.6931471805599453094;
    const double MAGIC = 6755399441055744.0;     // 1.5 * 2^52
    double t = x * LOG2E;
    double c = t + MAGIC;
    double n = c - MAGIC;                         // rint(t)
    int ni = (int)__double2loint(c);
    double g = (t - n) * LN2;
    double r = 2.505210838544172e-08;
    r = fma(r, g, 2.755731922398589e-07);
    r = fma(r, g, 2.7557319223985893e-06);
    r = fma(r, g, 2.48015873015873e-05);
    r = fma(r, g, 1.984126984126984e-04);
    r = fma(r, g, 1.388888888888889e-03);
    r = fma(r, g, 8.333333333333333e-03);
    r = fma(r, g, 4.1666666666666664e-02);
    r = fma(r, g, 1.6666666666666666e-01);
    r = fma(r, g, 0.5);
    r = fma(r, g, 1.0);
    r = fma(r, g, 1.0);
    double sc = __hiloint2double((1023 + ni) << 20, 0);   // 2^n
    return r * sc;
}

static __device__ __forceinline__ double fast_rcp(double x) {
    double r = (double)(1.0f / (float)x);
    r = r * (2.0 - x * r);
    r = r * (2.0 - x * r);
    return r;
}

// ---------------- Kernel A: memory norms + f16 hi/lo split + raw bf16 transpose ----------
__global__ __launch_bounds__(256) void prep_mem_kernel(const float* __restrict__ memory,
                                                       _Float16* __restrict__ mem_h,
                                                       _Float16* __restrict__ mem_L,
                                                       short* __restrict__ memT_bf) {
    int m = blockIdx.x;      // 0..511
    int t = threadIdx.x;
    double ss = 0.0;
    for (int c = t; c < CC; c += 256) {
        float v = memory[m * CC + c];
        ss += (double)v * (double)v;
    }
    #pragma unroll
    for (int off = 32; off > 0; off >>= 1) ss += __shfl_xor(ss, off);
    __shared__ double red[4];
    __shared__ double invs;
    if ((t & 63) == 0) red[t >> 6] = ss;
    __syncthreads();
    if (t == 0) {
        double tot = red[0] + red[1] + red[2] + red[3];
        invs = 1.0 / fmax(sqrt(tot), 1e-12);
    }
    __syncthreads();
    float inv = (float)invs;
    for (int c = t; c < CC; c += 256) {
        float v  = memory[m * CC + c];
        float nv = v * inv;
        _Float16 h = (_Float16)nv;
        float r1 = nv - (float)h;
        mem_h[m * CC + c] = h;
        mem_L[m * CC + c] = (_Float16)(r1 * SPLIT_SC);
        memT_bf[c * MM + m] = f2bf(v);
    }
}

// ---------------- Kernel B: scores GEMM, f16 2-split, 128x128 block, 8 waves ----------
// BM=128 x BN=128 x BK=32. 512 thr = 8 waves; wave (wr=wv>>1 0..3, wc=wv&1) = 32r x 64c.
// acc[fc][fn]: row = row0 + wr*32 + fc*16 + (lane>>4)*4 + reg,
//              col = colblk*128 + wc*64 + fn*16 + (lane&15).
// LDS rows are 32 f16 (64B), XOR-swizzled: idx ^ ((row&7)<<3) -> uniform 2-way (free).
#define SWZ(row_, k_) ((((row_) << 5) + (k_)) ^ (((row_) & 7) << 3))
__global__ __launch_bounds__(512, 4) void scores_gemm_kernel(const float* __restrict__ z,
                                                             const _Float16* __restrict__ mem_h,
                                                             const _Float16* __restrict__ mem_L,
                                                             float* __restrict__ out_scores,
                                                             double* __restrict__ zinv_ws) {
    __shared__ _Float16 AT[2][2][4096];   // [buf][h/L][swz(row,k)] 32 KB
    __shared__ _Float16 BT[2][2][4096];   // 32 KB
    __shared__ double ssred[512];

    const int t    = threadIdx.x;
    const int lane = t & 63;
    const int wv   = t >> 6;
    const int lrow = lane & 15;
    const int gk   = lane >> 4;
    const int wr   = wv >> 1, wc = wv & 1;
    // XCD-bijective decode: 4 col-siblings of a rowblock share dispatch slot mod 8
    const int d = blockIdx.x;                 // 0..1023
    const int colblk = (d >> 3) & 3;
    const int rowblk = (d & 7) | ((d >> 5) << 3);   // 0..255
    const int row0 = rowblk * 128;
    const int b    = row0 >> 10;
    const int n0   = row0 & 1023;
    const int cB0  = colblk * 128;

    // A staging: thread feeds row an (0..127), k-chunk ak8 = (t>>7)*8
    const int an  = t & 127;
    const int ak8 = (t >> 7) * 8;
    const float* zA = z + (size_t)b * ZSTRIDE + n0 + an;
    // B staging: thread feeds col bc (0..127), k-chunk kc = (t&3)*8, both planes
    const int bc = t >> 2;
    const int kc = (t & 3) * 8;
    const _Float16* mhB = mem_h + (size_t)(cB0 + bc) * CC + kc;
    const _Float16* mLB = mem_L + (size_t)(cB0 + bc) * CC + kc;

    double ss = 0.0;
    f32x4 am[2][4], ax[2][4];
    #pragma unroll
    for (int fc = 0; fc < 2; ++fc)
        #pragma unroll
        for (int fn = 0; fn < 4; ++fn) {
            am[fc][fn] = (f32x4){0.f, 0.f, 0.f, 0.f};
            ax[fc][fn] = (f32x4){0.f, 0.f, 0.f, 0.f};
        }

    #define LOADS(kt_, av_, bh_, bl_)                                          \
        do {                                                                   \
            _Pragma("unroll")                                                  \
            for (int j = 0; j < 8; ++j)                                        \
                av_[j] = zA[(size_t)((kt_) * 32 + ak8 + j) * NN];              \
            bh_ = *reinterpret_cast<const f16x8*>(mhB + (kt_) * 32);           \
            bl_ = *reinterpret_cast<const f16x8*>(mLB + (kt_) * 32);           \
        } while (0)

    #define WRITES(bb_, av_, bh_, bl_)                                         \
        do {                                                                   \
            f16x8 h8, l8;                                                      \
            _Pragma("unroll")                                                  \
            for (int j = 0; j < 8; ++j) {                                      \
                float v = av_[j];                                              \
                ss = fma((double)v, (double)v, ss);                            \
                _Float16 h = (_Float16)v;                                      \
                h8[j] = h;                                                     \
                l8[j] = (_Float16)((v - (float)h) * SPLIT_SC);                 \
            }                                                                  \
            *reinterpret_cast<f16x8*>(&AT[bb_][0][SWZ(an, ak8)]) = h8;         \
            *reinterpret_cast<f16x8*>(&AT[bb_][1][SWZ(an, ak8)]) = l8;         \
            *reinterpret_cast<f16x8*>(&BT[bb_][0][SWZ(bc, kc)])  = bh_;        \
            *reinterpret_cast<f16x8*>(&BT[bb_][1][SWZ(bc, kc)])  = bl_;        \
        } while (0)

    {   // prologue: stage kt=0
        float av[8]; f16x8 bh8, bl8;
        LOADS(0, av, bh8, bl8);
        WRITES(0, av, bh8, bl8);
    }
    __syncthreads();

    #pragma unroll 1
    for (int kt = 0; kt < 24; ++kt) {
        const int cur = kt & 1;
        float av[8]; f16x8 bh8, bl8;
        if (kt < 23) LOADS(kt + 1, av, bh8, bl8);   // T14: issue early

        f16x8 ah[2], aL[2];
        #pragma unroll
        for (int fc = 0; fc < 2; ++fc) {
            ah[fc] = *reinterpret_cast<const f16x8*>(&AT[cur][0][SWZ(wr * 32 + fc * 16 + lrow, gk * 8)]);
            aL[fc] = *reinterpret_cast<const f16x8*>(&AT[cur][1][SWZ(wr * 32 + fc * 16 + lrow, gk * 8)]);
        }
        f16x8 bh[4], bL[4];
        #pragma unroll
        for (int fn = 0; fn < 4; ++fn) {
            bh[fn] = *reinterpret_cast<const f16x8*>(&BT[cur][0][SWZ(wc * 64 + fn * 16 + lrow, gk * 8)]);
            bL[fn] = *reinterpret_cast<const f16x8*>(&BT[cur][1][SWZ(wc * 64 + fn * 16 + lrow, gk * 8)]);
        }
        #pragma unroll
        for (int fn = 0; fn < 4; ++fn)
            #pragma unroll
            for (int fc = 0; fc < 2; ++fc) {
                am[fc][fn] = __builtin_amdgcn_mfma_f32_16x16x32_f16(ah[fc], bh[fn], am[fc][fn], 0, 0, 0);
                ax[fc][fn] = __builtin_amdgcn_mfma_f32_16x16x32_f16(aL[fc], bh[fn], ax[fc][fn], 0, 0, 0);
                ax[fc][fn] = __builtin_amdgcn_mfma_f32_16x16x32_f16(ah[fc], bL[fn], ax[fc][fn], 0, 0, 0);
            }

        if (kt < 23) WRITES(cur ^ 1, av, bh8, bl8);  // write-late into other buffer
        __syncthreads();
    }
    #undef LOADS
    #undef WRITES

    // ---- store raw scores ----
    #pragma unroll
    for (int fc = 0; fc < 2; ++fc)
        #pragma unroll
        for (int fn = 0; fn < 4; ++fn)
            #pragma unroll
            for (int rg = 0; rg < 4; ++rg) {
                int row = row0 + wr * 32 + fc * 16 + gk * 4 + rg;
                int col = cB0 + wc * 64 + fn * 16 + lrow;
                out_scores[(size_t)row * MM + col] = am[fc][fn][rg] + ax[fc][fn][rg] * INV_SC;
            }

    // ---- z row inverse norms ----
    ssred[t] = ss;
    __syncthreads();
    if (colblk == 0 && t < 128) {
        double tot = ssred[t] + ssred[t + 128] + ssred[t + 256] + ssred[t + 384];
        zinv_ws[row0 + t] = 1.0 / fmax(sqrt(tot), 1e-12);
    }
}
#undef SWZ

// ---------------- Kernel C: in-place softmax + hardshrink + renorm (f64) -------
__global__ __launch_bounds__(256) void epilogue_kernel(float* __restrict__ attn,
                                                       const double* __restrict__ zinv_ws) {
    const int t    = threadIdx.x;
    const int lane = t & 63;
    const int wv   = t >> 6;
    const int row0 = blockIdx.x * 64;

    #pragma unroll 1
    for (int i = 0; i < 16; ++i) {
        int row = row0 + wv * 16 + i;
        double zi = zinv_ws[row];
        float* rp = attn + (size_t)row * MM;
        f32x4 x0 = *reinterpret_cast<const f32x4*>(&rp[lane * 4]);
        f32x4 x1 = *reinterpret_cast<const f32x4*>(&rp[256 + lane * 4]);
        double s0 = (double)x0[0] * zi, s1 = (double)x0[1] * zi;
        double s2 = (double)x0[2] * zi, s3 = (double)x0[3] * zi;
        double s4 = (double)x1[0] * zi, s5 = (double)x1[1] * zi;
        double s6 = (double)x1[2] * zi, s7 = (double)x1[3] * zi;
        double mx = fmax(fmax(fmax(s0, s1), fmax(s2, s3)),
                         fmax(fmax(s4, s5), fmax(s6, s7)));
        #pragma unroll
        for (int off = 32; off > 0; off >>= 1) mx = fmax(mx, __shfl_xor(mx, off));
        double p0 = fast_exp_neg(s0 - mx), p1 = fast_exp_neg(s1 - mx);
        double p2 = fast_exp_neg(s2 - mx), p3 = fast_exp_neg(s3 - mx);
        double p4 = fast_exp_neg(s4 - mx), p5 = fast_exp_neg(s5 - mx);
        double p6 = fast_exp_neg(s6 - mx), p7 = fast_exp_neg(s7 - mx);
        double Z = ((p0 + p1) + (p2 + p3)) + ((p4 + p5) + (p6 + p7));
        #pragma unroll
        for (int off = 32; off > 0; off >>= 1) Z += __shfl_xor(Z, off);
        double iZ = fast_rcp(Z);
        const double LAM = 1.0 / 512.0;
        double w0 = p0 * iZ, w1 = p1 * iZ, w2 = p2 * iZ, w3 = p3 * iZ;
        double w4 = p4 * iZ, w5 = p5 * iZ, w6 = p6 * iZ, w7 = p7 * iZ;
        double d0 = w0 - LAM, d1 = w1 - LAM, d2 = w2 - LAM, d3 = w3 - LAM;
        double d4 = w4 - LAM, d5 = w5 - LAM, d6 = w6 - LAM, d7 = w7 - LAM;
        double e0 = (d0 > 0.0 ? d0 : 0.0) * w0 * fast_rcp(fabs(d0) + 1e-8);
        double e1 = (d1 > 0.0 ? d1 : 0.0) * w1 * fast_rcp(fabs(d1) + 1e-8);
        double e2 = (d2 > 0.0 ? d2 : 0.0) * w2 * fast_rcp(fabs(d2) + 1e-8);
        double e3 = (d3 > 0.0 ? d3 : 0.0) * w3 * fast_rcp(fabs(d3) + 1e-8);
        double e4 = (d4 > 0.0 ? d4 : 0.0) * w4 * fast_rcp(fabs(d4) + 1e-8);
        double e5 = (d5 > 0.0 ? d5 : 0.0) * w5 * fast_rcp(fabs(d5) + 1e-8);
        double e6 = (d6 > 0.0 ? d6 : 0.0) * w6 * fast_rcp(fabs(d6) + 1e-8);
        double e7 = (d7 > 0.0 ? d7 : 0.0) * w7 * fast_rcp(fabs(d7) + 1e-8);
        double S = ((e0 + e1) + (e2 + e3)) + ((e4 + e5) + (e6 + e7));
        #pragma unroll
        for (int off = 32; off > 0; off >>= 1) S += __shfl_xor(S, off);
        double rinv = fast_rcp(S + 1e-8);
        f32x4 o0 = { (float)(e0 * rinv), (float)(e1 * rinv),
                     (float)(e2 * rinv), (float)(e3 * rinv) };
        f32x4 o1 = { (float)(e4 * rinv), (float)(e5 * rinv),
                     (float)(e6 * rinv), (float)(e7 * rinv) };
        *reinterpret_cast<f32x4*>(&rp[lane * 4])       = o0;
        *reinterpret_cast<f32x4*>(&rp[256 + lane * 4]) = o1;
    }
}

// ---------------- Kernel D: z_hat = attn @ memory via bf16 MFMA ----------------
// 1D grid 3072, XCD-bijective: a rowblock's 12 c-siblings are consecutive in
// the same XCD's dispatch stream -> its 256KB attn slice stays L2-hot.
__global__ __launch_bounds__(256) void readout_kernel(const short* __restrict__ memT_bf,
                                                      const float* __restrict__ attn,
                                                      float* __restrict__ out) {
    __shared__ short At[64][40];    // 64 c-rows x 32 k, padded
    __shared__ short Bt[128][40];   // 128 n-rows x 32 k
    int t = threadIdx.x;
    const int d  = blockIdx.x;              // 0..3071
    const int xs = d & 7;
    const int hi = d >> 3;                  // 0..383
    const int c0idx  = hi % 12;
    const int rowmid = hi / 12;             // 0..31
    const int rb128  = xs | (rowmid << 3);  // 0..255
    int c0     = c0idx * 64;
    int rowblk = rb128 * 128;
    int b  = rowblk >> 10;
    int nb = rowblk & 1023;
    int lane = t & 63, wv = t >> 6;

    f32x4 acc[4][2];
    #pragma unroll
    for (int fc = 0; fc < 4; ++fc)
        #pragma unroll
        for (int fn = 0; fn < 2; ++fn) acc[fc][fn] = (f32x4){0.f, 0.f, 0.f, 0.f};

    for (int m0 = 0; m0 < MM; m0 += 32) {
        __syncthreads();
        {   // stage A: 64 x 32 bf16
            int r = t >> 2, ko = (t & 3) * 8;
            short8 v = *reinterpret_cast<const short8*>(&memT_bf[(c0 + r) * MM + m0 + ko]);
            *reinterpret_cast<short8*>(&At[r][ko]) = v;
        }
        {   // stage B: 128 x 32, attn f32 -> bf16, vectorized
            int r = t >> 1, ko = (t & 1) * 16;
            const f32x4* src = reinterpret_cast<const f32x4*>(
                &attn[(size_t)(rowblk + r) * MM + m0 + ko]);
            f32x4 v0 = src[0], v1 = src[1], v2 = src[2], v3 = src[3];
            short8 s0 = { f2bf(v0[0]), f2bf(v0[1]), f2bf(v0[2]), f2bf(v0[3]),
                          f2bf(v1[0]), f2bf(v1[1]), f2bf(v1[2]), f2bf(v1[3]) };
            short8 s1 = { f2bf(v2[0]), f2bf(v2[1]), f2bf(v2[2]), f2bf(v2[3]),
                          f2bf(v3[0]), f2bf(v3[1]), f2bf(v3[2]), f2bf(v3[3]) };
            *reinterpret_cast<short8*>(&Bt[r][ko])     = s0;
            *reinterpret_cast<short8*>(&Bt[r][ko + 8]) = s1;
        }
        __syncthreads();
        short8 af[4], bfr[2];
        #pragma unroll
        for (int fc = 0; fc < 4; ++fc)
            af[fc] = *reinterpret_cast<const short8*>(&At[fc * 16 + (lane & 15)][(lane >> 4) * 8]);
        #pragma unroll
        for (int fn = 0; fn < 2; ++fn)
            bfr[fn] = *reinterpret_cast<const short8*>(&Bt[wv * 32 + fn * 16 + (lane & 15)][(lane >> 4) * 8]);
        #pragma unroll
        for (int fc = 0; fc < 4; ++fc)
            #pragma unroll
            for (int fn = 0; fn < 2; ++fn)
                acc[fc][fn] = __builtin_amdgcn_mfma_f32_16x16x32_bf16(af[fc], bfr[fn], acc[fc][fn], 0, 0, 0);
    }

    int cg = lane >> 4, cl = lane & 15;
    #pragma unroll
    for (int fc = 0; fc < 4; ++fc)
        #pragma unroll
        for (int fn = 0; fn < 2; ++fn)
            #pragma unroll
            for (int reg = 0; reg < 4; ++reg) {
                int c = c0 + fc * 16 + cg * 4 + reg;
                int n = nb + wv * 32 + fn * 16 + cl;
                out[(size_t)b * ZSTRIDE + (size_t)c * NN + n] = acc[fc][fn][reg];
            }
}

extern "C" void kernel_launch(void* const* d_in, const int* in_sizes, int n_in,
                              void* d_out, int out_size, void* d_ws, size_t ws_size,
                              hipStream_t stream) {
    const float* z      = (const float*)d_in[0];
    const float* memory = (const float*)d_in[1];
    float* out      = (float*)d_out;
    float* out_attn = out + OUT_ATTN_OFF;

    char* wsb = (char*)d_ws;
    _Float16* mem_h   = (_Float16*)wsb;               // 786432 B
    _Float16* mem_L   = (_Float16*)(wsb + 786432);    // 786432 B
    short*    memT_bf = (short*)(wsb + 1572864);      // 786432 B
    double*   zinv_ws = (double*)(wsb + 2359296);     // 262144 B

    prep_mem_kernel<<<512, 256, 0, stream>>>(memory, mem_h, mem_L, memT_bf);
    scores_gemm_kernel<<<1024, 512, 0, stream>>>(z, mem_h, mem_L, out_attn, zinv_ws);
    epilogue_kernel<<<RR / 64, 256, 0, stream>>>(out_attn, zinv_ws);
    readout_kernel<<<3072, 256, 0, stream>>>(memT_bf, out_attn, out);
}

// Round 10
// 197.339 us; speedup vs baseline: 1.9877x; 1.0524x over previous
//
#include <hip/hip_runtime.h>
#include <hip/hip_bf16.h>
#include <math.h>

typedef short short8 __attribute__((ext_vector_type(8)));
typedef float f32x4 __attribute__((ext_vector_type(4)));
typedef _Float16 f16x8 __attribute__((ext_vector_type(8)));

#define CC 768
#define NN 1024
#define RR 32768
#define MM 512
#define ZSTRIDE 786432      // C*H*W
#define OUT_ATTN_OFF 25165824
#define SPLIT_SC 2048.0f
#define INV_SC   (1.0f / 2048.0f)

static __device__ __forceinline__ short f2bf(float f) {
    __hip_bfloat16 h = __float2bfloat16(f);
    return *reinterpret_cast<short*>(&h);
}

// fast exp for x in [-2.5, +1e-6], f64 accuracy ~1e-14 rel, branch-free
static __device__ __forceinline__ double fast_exp_neg(double x) {
    const double LOG2E = 1.4426950408889634074;
    const double LN2   = 0.6931471805599453094;
    const double MAGIC = 6755399441055744.0;     // 1.5 * 2^52
    double t = x * LOG2E;
    double c = t + MAGIC;
    double n = c - MAGIC;                         // rint(t)
    int ni = (int)__double2loint(c);
    double g = (t - n) * LN2;
    double r = 2.505210838544172e-08;
    r = fma(r, g, 2.755731922398589e-07);
    r = fma(r, g, 2.7557319223985893e-06);
    r = fma(r, g, 2.48015873015873e-05);
    r = fma(r, g, 1.984126984126984e-04);
    r = fma(r, g, 1.388888888888889e-03);
    r = fma(r, g, 8.333333333333333e-03);
    r = fma(r, g, 4.1666666666666664e-02);
    r = fma(r, g, 1.6666666666666666e-01);
    r = fma(r, g, 0.5);
    r = fma(r, g, 1.0);
    r = fma(r, g, 1.0);
    double sc = __hiloint2double((1023 + ni) << 20, 0);   // 2^n
    return r * sc;
}

static __device__ __forceinline__ double fast_rcp(double x) {
    double r = (double)(1.0f / (float)x);
    r = r * (2.0 - x * r);
    r = r * (2.0 - x * r);
    return r;
}

// ---------------- Kernel A: memory norms + f16 hi/lo split + raw bf16 transpose ----------
__global__ __launch_bounds__(256) void prep_mem_kernel(const float* __restrict__ memory,
                                                       _Float16* __restrict__ mem_h,
                                                       _Float16* __restrict__ mem_L,
                                                       short* __restrict__ memT_bf) {
    int m = blockIdx.x;      // 0..511
    int t = threadIdx.x;
    double ss = 0.0;
    for (int c = t; c < CC; c += 256) {
        float v = memory[m * CC + c];
        ss += (double)v * (double)v;
    }
    #pragma unroll
    for (int off = 32; off > 0; off >>= 1) ss += __shfl_xor(ss, off);
    __shared__ double red[4];
    __shared__ double invs;
    if ((t & 63) == 0) red[t >> 6] = ss;
    __syncthreads();
    if (t == 0) {
        double tot = red[0] + red[1] + red[2] + red[3];
        invs = 1.0 / fmax(sqrt(tot), 1e-12);
    }
    __syncthreads();
    float inv = (float)invs;
    for (int c = t; c < CC; c += 256) {
        float v  = memory[m * CC + c];
        float nv = v * inv;
        _Float16 h = (_Float16)nv;
        float r1 = nv - (float)h;
        mem_h[m * CC + c] = h;
        mem_L[m * CC + c] = (_Float16)(r1 * SPLIT_SC);
        memT_bf[c * MM + m] = f2bf(v);
    }
}

// ---------------- Kernel B: scores GEMM, f16 2-split, 128x128 block, 4 fat waves --------
// BM=128 x BN=128 x BK=32. 256 thr = 4 waves (2x2); wave = 64r x 64c.
// acc[fc][fn]: row = row0 + wr*64 + fc*16 + (lane>>4)*4 + reg,
//              col = cB0 + wc*64 + fn*16 + (lane&15).
// LDS rows 32 f16 (64B), XOR-swizzled: idx ^ ((row&7)<<3).
#define SWZ(row_, k_) ((((row_) << 5) + (k_)) ^ (((row_) & 7) << 3))
__global__ __launch_bounds__(256, 2) void scores_gemm_kernel(const float* __restrict__ z,
                                                             const _Float16* __restrict__ mem_h,
                                                             const _Float16* __restrict__ mem_L,
                                                             float* __restrict__ out_scores,
                                                             double* __restrict__ zinv_ws) {
    __shared__ _Float16 AT[2][2][4096];   // [buf][h/L][swz(row,k)] 32 KB
    __shared__ _Float16 BT[2][2][4096];   // 32 KB
    __shared__ double ssred[256];

    const int t    = threadIdx.x;
    const int lane = t & 63;
    const int wv   = t >> 6;
    const int lrow = lane & 15;
    const int gk   = lane >> 4;
    const int wr   = wv >> 1, wc = wv & 1;
    // XCD-bijective decode: 4 col-siblings of a rowblock share dispatch slot mod 8
    const int d = blockIdx.x;                 // 0..1023
    const int colblk = (d >> 3) & 3;
    const int rowblk = (d & 7) | ((d >> 5) << 3);   // 0..255
    const int row0 = rowblk * 128;
    const int b    = row0 >> 10;
    const int n0   = row0 & 1023;
    const int cB0  = colblk * 128;

    // A staging: thread feeds row an (0..127), 16 k at ak16 = (t>>7)*16
    const int an   = t & 127;
    const int ak16 = (t >> 7) * 16;
    const float* zA = z + (size_t)b * ZSTRIDE + n0 + an;
    // B staging: thread feeds col bc (0..127), 16 k at kc = (t&1)*16, both planes
    const int bc = t >> 1;
    const int kc = (t & 1) * 16;
    const _Float16* mhB = mem_h + (size_t)(cB0 + bc) * CC + kc;
    const _Float16* mLB = mem_L + (size_t)(cB0 + bc) * CC + kc;

    double ss = 0.0;
    f32x4 am[4][4], ax[4][4];
    #pragma unroll
    for (int fc = 0; fc < 4; ++fc)
        #pragma unroll
        for (int fn = 0; fn < 4; ++fn) {
            am[fc][fn] = (f32x4){0.f, 0.f, 0.f, 0.f};
            ax[fc][fn] = (f32x4){0.f, 0.f, 0.f, 0.f};
        }

    #define LOADS(kt_, av_, bh_, bl_)                                          \
        do {                                                                   \
            _Pragma("unroll")                                                  \
            for (int j = 0; j < 16; ++j)                                       \
                av_[j] = zA[(size_t)((kt_) * 32 + ak16 + j) * NN];             \
            bh_[0] = *reinterpret_cast<const f16x8*>(mhB + (kt_) * 32);        \
            bh_[1] = *reinterpret_cast<const f16x8*>(mhB + (kt_) * 32 + 8);    \
            bl_[0] = *reinterpret_cast<const f16x8*>(mLB + (kt_) * 32);        \
            bl_[1] = *reinterpret_cast<const f16x8*>(mLB + (kt_) * 32 + 8);    \
        } while (0)

    #define WRITES(bb_, av_, bh_, bl_)                                         \
        do {                                                                   \
            f16x8 h8a, l8a, h8b, l8b;                                          \
            _Pragma("unroll")                                                  \
            for (int j = 0; j < 8; ++j) {                                      \
                float v = av_[j];                                              \
                ss = fma((double)v, (double)v, ss);                            \
                _Float16 h = (_Float16)v;                                      \
                h8a[j] = h;                                                    \
                l8a[j] = (_Float16)((v - (float)h) * SPLIT_SC);                \
            }                                                                  \
            _Pragma("unroll")                                                  \
            for (int j = 0; j < 8; ++j) {                                      \
                float v = av_[8 + j];                                          \
                ss = fma((double)v, (double)v, ss);                            \
                _Float16 h = (_Float16)v;                                      \
                h8b[j] = h;                                                    \
                l8b[j] = (_Float16)((v - (float)h) * SPLIT_SC);                \
            }                                                                  \
            *reinterpret_cast<f16x8*>(&AT[bb_][0][SWZ(an, ak16)])     = h8a;   \
            *reinterpret_cast<f16x8*>(&AT[bb_][0][SWZ(an, ak16 + 8)]) = h8b;   \
            *reinterpret_cast<f16x8*>(&AT[bb_][1][SWZ(an, ak16)])     = l8a;   \
            *reinterpret_cast<f16x8*>(&AT[bb_][1][SWZ(an, ak16 + 8)]) = l8b;   \
            *reinterpret_cast<f16x8*>(&BT[bb_][0][SWZ(bc, kc)])       = bh_[0];\
            *reinterpret_cast<f16x8*>(&BT[bb_][0][SWZ(bc, kc + 8)])   = bh_[1];\
            *reinterpret_cast<f16x8*>(&BT[bb_][1][SWZ(bc, kc)])       = bl_[0];\
            *reinterpret_cast<f16x8*>(&BT[bb_][1][SWZ(bc, kc + 8)])   = bl_[1];\
        } while (0)

    {   // prologue: stage kt=0
        float av[16]; f16x8 bh8[2], bl8[2];
        LOADS(0, av, bh8, bl8);
        WRITES(0, av, bh8, bl8);
    }
    __syncthreads();

    #pragma unroll 1
    for (int kt = 0; kt < 24; ++kt) {
        const int cur = kt & 1;
        float av[16]; f16x8 bh8[2], bl8[2];
        if (kt < 23) LOADS(kt + 1, av, bh8, bl8);   // T14: issue early

        f16x8 ah[4], aL[4];
        #pragma unroll
        for (int fc = 0; fc < 4; ++fc) {
            ah[fc] = *reinterpret_cast<const f16x8*>(&AT[cur][0][SWZ(wr * 64 + fc * 16 + lrow, gk * 8)]);
            aL[fc] = *reinterpret_cast<const f16x8*>(&AT[cur][1][SWZ(wr * 64 + fc * 16 + lrow, gk * 8)]);
        }
        f16x8 bh[4], bL[4];
        #pragma unroll
        for (int fn = 0; fn < 4; ++fn) {
            bh[fn] = *reinterpret_cast<const f16x8*>(&BT[cur][0][SWZ(wc * 64 + fn * 16 + lrow, gk * 8)]);
            bL[fn] = *reinterpret_cast<const f16x8*>(&BT[cur][1][SWZ(wc * 64 + fn * 16 + lrow, gk * 8)]);
        }
        #pragma unroll
        for (int fn = 0; fn < 4; ++fn)
            #pragma unroll
            for (int fc = 0; fc < 4; ++fc) {
                am[fc][fn] = __builtin_amdgcn_mfma_f32_16x16x32_f16(ah[fc], bh[fn], am[fc][fn], 0, 0, 0);
                ax[fc][fn] = __builtin_amdgcn_mfma_f32_16x16x32_f16(aL[fc], bh[fn], ax[fc][fn], 0, 0, 0);
                ax[fc][fn] = __builtin_amdgcn_mfma_f32_16x16x32_f16(ah[fc], bL[fn], ax[fc][fn], 0, 0, 0);
            }

        if (kt < 23) WRITES(cur ^ 1, av, bh8, bl8);  // write-late into other buffer
        __syncthreads();
    }
    #undef LOADS
    #undef WRITES

    // ---- store raw scores ----
    #pragma unroll
    for (int fc = 0; fc < 4; ++fc)
        #pragma unroll
        for (int fn = 0; fn < 4; ++fn)
            #pragma unroll
            for (int rg = 0; rg < 4; ++rg) {
                int row = row0 + wr * 64 + fc * 16 + gk * 4 + rg;
                int col = cB0 + wc * 64 + fn * 16 + lrow;
                out_scores[(size_t)row * MM + col] = am[fc][fn][rg] + ax[fc][fn][rg] * INV_SC;
            }

    // ---- z row inverse norms (thread t covers half the k-range of row an) ----
    ssred[t] = ss;
    __syncthreads();
    if (colblk == 0 && t < 128) {
        double tot = ssred[t] + ssred[t + 128];
        zinv_ws[row0 + t] = 1.0 / fmax(sqrt(tot), 1e-12);
    }
}
#undef SWZ

// ---------------- Kernel C: in-place softmax + hardshrink + renorm (f64) -------
__global__ __launch_bounds__(256) void epilogue_kernel(float* __restrict__ attn,
                                                       const double* __restrict__ zinv_ws) {
    const int t    = threadIdx.x;
    const int lane = t & 63;
    const int wv   = t >> 6;
    const int row0 = blockIdx.x * 64;

    #pragma unroll 1
    for (int i = 0; i < 16; ++i) {
        int row = row0 + wv * 16 + i;
        double zi = zinv_ws[row];
        float* rp = attn + (size_t)row * MM;
        f32x4 x0 = *reinterpret_cast<const f32x4*>(&rp[lane * 4]);
        f32x4 x1 = *reinterpret_cast<const f32x4*>(&rp[256 + lane * 4]);
        double s0 = (double)x0[0] * zi, s1 = (double)x0[1] * zi;
        double s2 = (double)x0[2] * zi, s3 = (double)x0[3] * zi;
        double s4 = (double)x1[0] * zi, s5 = (double)x1[1] * zi;
        double s6 = (double)x1[2] * zi, s7 = (double)x1[3] * zi;
        double mx = fmax(fmax(fmax(s0, s1), fmax(s2, s3)),
                         fmax(fmax(s4, s5), fmax(s6, s7)));
        #pragma unroll
        for (int off = 32; off > 0; off >>= 1) mx = fmax(mx, __shfl_xor(mx, off));
        double p0 = fast_exp_neg(s0 - mx), p1 = fast_exp_neg(s1 - mx);
        double p2 = fast_exp_neg(s2 - mx), p3 = fast_exp_neg(s3 - mx);
        double p4 = fast_exp_neg(s4 - mx), p5 = fast_exp_neg(s5 - mx);
        double p6 = fast_exp_neg(s6 - mx), p7 = fast_exp_neg(s7 - mx);
        double Z = ((p0 + p1) + (p2 + p3)) + ((p4 + p5) + (p6 + p7));
        #pragma unroll
        for (int off = 32; off > 0; off >>= 1) Z += __shfl_xor(Z, off);
        double iZ = fast_rcp(Z);
        const double LAM = 1.0 / 512.0;
        double w0 = p0 * iZ, w1 = p1 * iZ, w2 = p2 * iZ, w3 = p3 * iZ;
        double w4 = p4 * iZ, w5 = p5 * iZ, w6 = p6 * iZ, w7 = p7 * iZ;
        double d0 = w0 - LAM, d1 = w1 - LAM, d2 = w2 - LAM, d3 = w3 - LAM;
        double d4 = w4 - LAM, d5 = w5 - LAM, d6 = w6 - LAM, d7 = w7 - LAM;
        double e0 = (d0 > 0.0 ? d0 : 0.0) * w0 * fast_rcp(fabs(d0) + 1e-8);
        double e1 = (d1 > 0.0 ? d1 : 0.0) * w1 * fast_rcp(fabs(d1) + 1e-8);
        double e2 = (d2 > 0.0 ? d2 : 0.0) * w2 * fast_rcp(fabs(d2) + 1e-8);
        double e3 = (d3 > 0.0 ? d3 : 0.0) * w3 * fast_rcp(fabs(d3) + 1e-8);
        double e4 = (d4 > 0.0 ? d4 : 0.0) * w4 * fast_rcp(fabs(d4) + 1e-8);
        double e5 = (d5 > 0.0 ? d5 : 0.0) * w5 * fast_rcp(fabs(d5) + 1e-8);
        double e6 = (d6 > 0.0 ? d6 : 0.0) * w6 * fast_rcp(fabs(d6) + 1e-8);
        double e7 = (d7 > 0.0 ? d7 : 0.0) * w7 * fast_rcp(fabs(d7) + 1e-8);
        double S = ((e0 + e1) + (e2 + e3)) + ((e4 + e5) + (e6 + e7));
        #pragma unroll
        for (int off = 32; off > 0; off >>= 1) S += __shfl_xor(S, off);
        double rinv = fast_rcp(S + 1e-8);
        f32x4 o0 = { (float)(e0 * rinv), (float)(e1 * rinv),
                     (float)(e2 * rinv), (float)(e3 * rinv) };
        f32x4 o1 = { (float)(e4 * rinv), (float)(e5 * rinv),
                     (float)(e6 * rinv), (float)(e7 * rinv) };
        *reinterpret_cast<f32x4*>(&rp[lane * 4])       = o0;
        *reinterpret_cast<f32x4*>(&rp[256 + lane * 4]) = o1;
    }
}

// ---------------- Kernel D: z_hat = attn @ memory via bf16 MFMA, 128x128 tiles ----------
// 1536 blocks (6 c-tiles x 256 rowblks), XCD-bijective; 256 thr = 4 waves (2x2),
// wave = 64c x 64n. acc[fc][fn].
__global__ __launch_bounds__(256, 3) void readout_kernel(const short* __restrict__ memT_bf,
                                                         const float* __restrict__ attn,
                                                         float* __restrict__ out) {
    __shared__ short At[128][40];   // 128 c-rows x 32 m, padded
    __shared__ short Bt[128][40];   // 128 n-rows x 32 m
    const int t = threadIdx.x;
    const int d  = blockIdx.x;              // 0..1535
    const int xs = d & 7;
    const int hi = d >> 3;                  // 0..191
    const int c0idx  = hi % 6;
    const int rowmid = hi / 6;              // 0..31
    const int rb     = xs | (rowmid << 3);  // 0..255
    const int c0     = c0idx * 128;
    const int rowblk = rb * 128;
    const int b  = rowblk >> 10;
    const int nb = rowblk & 1023;
    const int lane = t & 63, wv = t >> 6;
    const int wcr = wv >> 1, wcc = wv & 1;
    const int lrow = lane & 15, gk = lane >> 4;

    f32x4 acc[4][4];
    #pragma unroll
    for (int fc = 0; fc < 4; ++fc)
        #pragma unroll
        for (int fn = 0; fn < 4; ++fn) acc[fc][fn] = (f32x4){0.f, 0.f, 0.f, 0.f};

    const int sr = t >> 1;           // staging row 0..127
    const int ko = (t & 1) * 16;     // m-chunk

    for (int m0 = 0; m0 < MM; m0 += 32) {
        __syncthreads();
        {   // stage A: 128 x 32 bf16 (memT)
            const short8* src = reinterpret_cast<const short8*>(
                &memT_bf[(c0 + sr) * MM + m0 + ko]);
            *reinterpret_cast<short8*>(&At[sr][ko])     = src[0];
            *reinterpret_cast<short8*>(&At[sr][ko + 8]) = src[1];
        }
        {   // stage B: 128 x 32, attn f32 -> bf16, vectorized
            const f32x4* src = reinterpret_cast<const f32x4*>(
                &attn[(size_t)(rowblk + sr) * MM + m0 + ko]);
            f32x4 v0 = src[0], v1 = src[1], v2 = src[2], v3 = src[3];
            short8 s0 = { f2bf(v0[0]), f2bf(v0[1]), f2bf(v0[2]), f2bf(v0[3]),
                          f2bf(v1[0]), f2bf(v1[1]), f2bf(v1[2]), f2bf(v1[3]) };
            short8 s1 = { f2bf(v2[0]), f2bf(v2[1]), f2bf(v2[2]), f2bf(v2[3]),
                          f2bf(v3[0]), f2bf(v3[1]), f2bf(v3[2]), f2bf(v3[3]) };
            *reinterpret_cast<short8*>(&Bt[sr][ko])     = s0;
            *reinterpret_cast<short8*>(&Bt[sr][ko + 8]) = s1;
        }
        __syncthreads();
        short8 af[4], bf[4];
        #pragma unroll
        for (int fc = 0; fc < 4; ++fc)
            af[fc] = *reinterpret_cast<const short8*>(&At[wcr * 64 + fc * 16 + lrow][gk * 8]);
        #pragma unroll
        for (int fn = 0; fn < 4; ++fn)
            bf[fn] = *reinterpret_cast<const short8*>(&Bt[wcc * 64 + fn * 16 + lrow][gk * 8]);
        #pragma unroll
        for (int fc = 0; fc < 4; ++fc)
            #pragma unroll
            for (int fn = 0; fn < 4; ++fn)
                acc[fc][fn] = __builtin_amdgcn_mfma_f32_16x16x32_bf16(af[fc], bf[fn], acc[fc][fn], 0, 0, 0);
    }

    #pragma unroll
    for (int fc = 0; fc < 4; ++fc)
        #pragma unroll
        for (int fn = 0; fn < 4; ++fn)
            #pragma unroll
            for (int reg = 0; reg < 4; ++reg) {
                int c = c0 + wcr * 64 + fc * 16 + gk * 4 + reg;
                int n = nb + wcc * 64 + fn * 16 + lrow;
                out[(size_t)b * ZSTRIDE + (size_t)c * NN + n] = acc[fc][fn][reg];
            }
}

extern "C" void kernel_launch(void* const* d_in, const int* in_sizes, int n_in,
                              void* d_out, int out_size, void* d_ws, size_t ws_size,
                              hipStream_t stream) {
    const float* z      = (const float*)d_in[0];
    const float* memory = (const float*)d_in[1];
    float* out      = (float*)d_out;
    float* out_attn = out + OUT_ATTN_OFF;

    char* wsb = (char*)d_ws;
    _Float16* mem_h   = (_Float16*)wsb;               // 786432 B
    _Float16* mem_L   = (_Float16*)(wsb + 786432);    // 786432 B
    short*    memT_bf = (short*)(wsb + 1572864);      // 786432 B
    double*   zinv_ws = (double*)(wsb + 2359296);     // 262144 B

    prep_mem_kernel<<<512, 256, 0, stream>>>(memory, mem_h, mem_L, memT_bf);
    scores_gemm_kernel<<<1024, 256, 0, stream>>>(z, mem_h, mem_L, out_attn, zinv_ws);
    epilogue_kernel<<<RR / 64, 256, 0, stream>>>(out_attn, zinv_ws);
    readout_kernel<<<1536, 256, 0, stream>>>(memT_bf, out_attn, out);
}